// Round 1
// baseline (76.017 us; speedup 1.0000x reference)
//
#include <hip/hip_runtime.h>
#include <math.h>

#define BB 32
#define NN 4096
#define DD 512
#define CC 5

// Pass 1: stream x once. Each block = (b, segment of N). 4 waves per block,
// each wave processes rows of the segment round-robin with an online-softmax
// weighted accumulator. Block combines waves in LDS, writes partial
// (m, l, acc[C][D]) per (b,seg) to workspace.
__global__ __launch_bounds__(256, 3)
void capsule_pass1(const float* __restrict__ x, const float* __restrict__ Wa,
                   float* __restrict__ acc_ws, float* __restrict__ ml_ws,
                   int S, int rows_per_seg)
{
    const int blk  = blockIdx.x;
    const int b    = blk / S;
    const int seg  = blk % S;
    const int tid  = threadIdx.x;
    const int lane = tid & 63;
    const int wid  = tid >> 6;   // 0..3

    // lane owns d in [d0, d0+4) and [d1, d1+4)
    const int d0 = lane * 4;
    const int d1 = 256 + lane * 4;

    // W_alpha fragments for this lane's 8 d's, kept in registers for the whole loop
    float wa[8][CC];
#pragma unroll
    for (int j = 0; j < 4; ++j) {
#pragma unroll
        for (int c = 0; c < CC; ++c) {
            wa[j][c]     = Wa[(d0 + j) * CC + c];
            wa[4 + j][c] = Wa[(d1 + j) * CC + c];
        }
    }

    float acc[CC][8];
    float m[CC], l[CC];
#pragma unroll
    for (int c = 0; c < CC; ++c) {
        m[c] = -INFINITY;
        l[c] = 0.0f;
#pragma unroll
        for (int j = 0; j < 8; ++j) acc[c][j] = 0.0f;
    }

    const float* xseg = x + ((size_t)b * NN + (size_t)seg * rows_per_seg) * DD;

    for (int i = wid; i < rows_per_seg; i += 4) {
        const float* xr = xseg + (size_t)i * DD;
        const float4 xa = *reinterpret_cast<const float4*>(xr + d0);
        const float4 xb = *reinterpret_cast<const float4*>(xr + d1);
        float xv[8] = {xa.x, xa.y, xa.z, xa.w, xb.x, xb.y, xb.z, xb.w};

        float e[CC];
#pragma unroll
        for (int c = 0; c < CC; ++c) {
            float s = 0.0f;
#pragma unroll
            for (int j = 0; j < 8; ++j) s = fmaf(xv[j], wa[j][c], s);
            e[c] = s;
        }
        // butterfly reduce across the 64-lane wave -> full sum in every lane
#pragma unroll
        for (int off = 1; off < 64; off <<= 1) {
#pragma unroll
            for (int c = 0; c < CC; ++c) e[c] += __shfl_xor(e[c], off, 64);
        }

        // online softmax-weighted accumulation (branch is wave-uniform)
#pragma unroll
        for (int c = 0; c < CC; ++c) {
            if (e[c] > m[c]) {
                const float s = __expf(m[c] - e[c]);   // 0 when m == -inf
                l[c] = l[c] * s + 1.0f;
#pragma unroll
                for (int j = 0; j < 8; ++j) acc[c][j] = fmaf(acc[c][j], s, xv[j]);
                m[c] = e[c];
            } else {
                const float pe = __expf(e[c] - m[c]);
                l[c] += pe;
#pragma unroll
                for (int j = 0; j < 8; ++j) acc[c][j] = fmaf(pe, xv[j], acc[c][j]);
            }
        }
    }

    // ---- combine the 4 waves ----
    __shared__ float s_ml[4][CC][2];
    __shared__ float s_acc[CC][DD];   // 10 KB

    if (lane == 0) {
#pragma unroll
        for (int c = 0; c < CC; ++c) {
            s_ml[wid][c][0] = m[c];
            s_ml[wid][c][1] = l[c];
        }
    }
    __syncthreads();

    float mb[CC], lb[CC], cw[CC];
#pragma unroll
    for (int c = 0; c < CC; ++c) {
        float mm = s_ml[0][c][0];
#pragma unroll
        for (int w = 1; w < 4; ++w) mm = fmaxf(mm, s_ml[w][c][0]);
        mb[c] = mm;
        float ll = 0.0f;
#pragma unroll
        for (int w = 0; w < 4; ++w) ll += __expf(s_ml[w][c][0] - mm) * s_ml[w][c][1];
        lb[c] = ll;
        cw[c] = __expf(s_ml[wid][c][0] - mm);   // this wave's rescale coeff
    }

    // waves deposit (rescaled) accumulators into LDS sequentially
    for (int w = 0; w < 4; ++w) {
        if (wid == w) {
#pragma unroll
            for (int c = 0; c < CC; ++c) {
#pragma unroll
                for (int j = 0; j < 8; ++j) {
                    const int d = (j < 4) ? (d0 + j) : (d1 + j - 4);
                    const float v = acc[c][j] * cw[c];
                    if (w == 0) s_acc[c][d] = v;
                    else        s_acc[c][d] += v;
                }
            }
        }
        __syncthreads();
    }

    // write block partials to workspace
    float* accp = acc_ws + (size_t)blk * CC * DD;
    const float* sa = &s_acc[0][0];
    for (int idx = tid; idx < CC * DD; idx += 256) accp[idx] = sa[idx];
    if (tid < CC) {
        ml_ws[((size_t)blk * CC + tid) * 2 + 0] = mb[tid];
        ml_ws[((size_t)blk * CC + tid) * 2 + 1] = lb[tid];
    }
}

// Pass 2: one block per (b,c). Combine S segment partials, normalize,
// epilogue p = tanh(v.w + b), r = p*v, write all three outputs.
__global__ __launch_bounds__(256)
void capsule_pass2(const float* __restrict__ acc_ws, const float* __restrict__ ml_ws,
                   const float* __restrict__ lin_w, const float* __restrict__ lin_b,
                   float* __restrict__ p_out, float* __restrict__ v_out,
                   float* __restrict__ r_out, int S)
{
    const int bc  = blockIdx.x;          // 0..B*C-1
    const int b   = bc / CC;
    const int c   = bc % CC;
    const int tid = threadIdx.x;

    __shared__ float s_w[64];
    __shared__ float s_red[4];
    __shared__ float s_p;

    // global max over segments (all threads redundantly; identical order -> identical value)
    float mg = -INFINITY;
    for (int s = 0; s < S; ++s)
        mg = fmaxf(mg, ml_ws[(((size_t)b * S + s) * CC + c) * 2]);
    float lg = 0.0f;
    for (int s = 0; s < S; ++s) {
        const float mw = ml_ws[(((size_t)b * S + s) * CC + c) * 2];
        const float lw = ml_ws[(((size_t)b * S + s) * CC + c) * 2 + 1];
        const float w  = __expf(mw - mg);
        lg += w * lw;
        if (tid == 0) s_w[s] = w;
    }
    __syncthreads();

    const float inv_l = 1.0f / lg;
    float v0 = 0.0f, v1 = 0.0f;
    for (int s = 0; s < S; ++s) {
        const float* ap = acc_ws + (((size_t)b * S + s) * CC + c) * DD;
        const float w = s_w[s];
        v0 = fmaf(w, ap[tid], v0);
        v1 = fmaf(w, ap[tid + 256], v1);
    }
    v0 *= inv_l;
    v1 *= inv_l;

    v_out[(size_t)bc * DD + tid]       = v0;
    v_out[(size_t)bc * DD + tid + 256] = v1;

    // dot(v, lin_w)
    float part = v0 * lin_w[tid] + v1 * lin_w[tid + 256];
#pragma unroll
    for (int off = 1; off < 64; off <<= 1) part += __shfl_xor(part, off, 64);
    if ((tid & 63) == 0) s_red[tid >> 6] = part;
    __syncthreads();
    if (tid == 0) {
        const float dot = s_red[0] + s_red[1] + s_red[2] + s_red[3] + lin_b[0];
        const float p = tanhf(dot);
        s_p = p;
        p_out[bc] = p;
    }
    __syncthreads();
    const float p = s_p;
    r_out[(size_t)bc * DD + tid]       = p * v0;
    r_out[(size_t)bc * DD + tid + 256] = p * v1;
}

extern "C" void kernel_launch(void* const* d_in, const int* in_sizes, int n_in,
                              void* d_out, int out_size, void* d_ws, size_t ws_size,
                              hipStream_t stream) {
    const float* x   = (const float*)d_in[0];
    const float* Wa  = (const float*)d_in[1];
    const float* lw  = (const float*)d_in[2];
    const float* lb  = (const float*)d_in[3];

    float* out   = (float*)d_out;
    float* p_out = out;                       // (B, C)
    float* v_out = out + BB * CC;             // (B, C, D)
    float* r_out = v_out + BB * CC * DD;      // (B, C, D)

    // choose segment count to fit workspace: need B*S*C*(D+2) floats
    int S = 32;
    while (S > 1 && (size_t)BB * S * CC * (DD + 2) * sizeof(float) > ws_size) S >>= 1;
    const int rows_per_seg = NN / S;

    float* acc_ws = (float*)d_ws;                        // B*S*C*D
    float* ml_ws  = acc_ws + (size_t)BB * S * CC * DD;   // B*S*C*2

    capsule_pass1<<<dim3(BB * S), dim3(256), 0, stream>>>(x, Wa, acc_ws, ml_ws, S, rows_per_seg);
    capsule_pass2<<<dim3(BB * CC), dim3(256), 0, stream>>>(acc_ws, ml_ws, lw, lb,
                                                           p_out, v_out, r_out, S);
}

// Round 2
// 64.188 us; speedup vs baseline: 1.1843x; 1.1843x over previous
//
#include <hip/hip_runtime.h>
#include <math.h>

#define BB 32
#define NN 4096
#define DD 512
#define CC 5

// Cheap wave-wide all-reduce add for one fp32 value.
// xor1/xor2/xor8 via DPP (VALU pipe), xor4/xor16 via ds_swizzle, xor32 via
// one ds_bpermute. 3 DS-pipe ops per value instead of 6 ds_bpermute that
// __shfl_xor would emit.
#define DPP_ADD(v, ctrl)                                                        \
    do {                                                                        \
        int _t = __builtin_amdgcn_update_dpp(0, __float_as_int(v), (ctrl),      \
                                             0xF, 0xF, true);                   \
        (v) += __int_as_float(_t);                                              \
    } while (0)

#define SWZ_ADD(v, imm)                                                         \
    do {                                                                        \
        int _t = __builtin_amdgcn_ds_swizzle(__float_as_int(v), (imm));         \
        (v) += __int_as_float(_t);                                              \
    } while (0)

static __device__ __forceinline__ float wave_allreduce_add(float v, int bidx32)
{
    // xor32 (cross-half) via bpermute
    v += __int_as_float(__builtin_amdgcn_ds_bpermute(bidx32, __float_as_int(v)));
    // xor16 via ds_swizzle BitMode (xor<<10 | and 0x1F)
    SWZ_ADD(v, 0x401F);
    // xor8 via DPP row_ror:8 (within-16 rotate by 8 == xor 8)
    DPP_ADD(v, 0x128);
    // xor4 via ds_swizzle
    SWZ_ADD(v, 0x101F);
    // xor2 via DPP quad_perm:[2,3,0,1]
    DPP_ADD(v, 0x4E);
    // xor1 via DPP quad_perm:[1,0,3,2]
    DPP_ADD(v, 0xB1);
    return v;
}

// Pass 1: stream x once. Each block = (b, segment of N). 4 waves per block,
// each wave processes rows of the segment round-robin with an online-softmax
// weighted accumulator. Block combines waves in LDS, writes partial
// (m, l, acc[C][D]) per (b,seg) to workspace.
__global__ __launch_bounds__(256, 3)
void capsule_pass1(const float* __restrict__ x, const float* __restrict__ Wa,
                   float* __restrict__ acc_ws, float* __restrict__ ml_ws,
                   int S, int rows_per_seg)
{
    const int blk  = blockIdx.x;
    const int b    = blk / S;
    const int seg  = blk % S;
    const int tid  = threadIdx.x;
    const int lane = tid & 63;
    const int wid  = tid >> 6;   // 0..3
    const int bidx32 = ((lane ^ 32) << 2);   // byte index for ds_bpermute xor32

    // lane owns d in [d0, d0+4) and [d1, d1+4)
    const int d0 = lane * 4;
    const int d1 = 256 + lane * 4;

    // W_alpha fragments: 20 contiguous floats per half (d0..d0+3 x 5 c's),
    // loaded as 5 float4 each. Indexed wa[j*5+c], all compile-time indices.
    float wal[20], wah[20];
    {
        const float4* pl = reinterpret_cast<const float4*>(Wa + d0 * CC);
        const float4* ph = reinterpret_cast<const float4*>(Wa + d1 * CC);
#pragma unroll
        for (int q = 0; q < 5; ++q) {
            float4 a = pl[q];
            wal[q * 4 + 0] = a.x; wal[q * 4 + 1] = a.y;
            wal[q * 4 + 2] = a.z; wal[q * 4 + 3] = a.w;
            float4 b4 = ph[q];
            wah[q * 4 + 0] = b4.x; wah[q * 4 + 1] = b4.y;
            wah[q * 4 + 2] = b4.z; wah[q * 4 + 3] = b4.w;
        }
    }

    float acc[CC][8];
    float m[CC], l[CC];
#pragma unroll
    for (int c = 0; c < CC; ++c) {
        m[c] = -INFINITY;
        l[c] = 0.0f;
#pragma unroll
        for (int j = 0; j < 8; ++j) acc[c][j] = 0.0f;
    }

    const float* xseg = x + ((size_t)b * NN + (size_t)seg * rows_per_seg) * DD;

#pragma unroll 2
    for (int i = wid; i < rows_per_seg; i += 4) {
        const float* xr = xseg + (size_t)i * DD;
        const float4 xa = *reinterpret_cast<const float4*>(xr + d0);
        const float4 xb = *reinterpret_cast<const float4*>(xr + d1);
        float xv[8] = {xa.x, xa.y, xa.z, xa.w, xb.x, xb.y, xb.z, xb.w};

        float e[CC];
#pragma unroll
        for (int c = 0; c < CC; ++c) {
            float s = 0.0f;
#pragma unroll
            for (int j = 0; j < 4; ++j) s = fmaf(xv[j], wal[j * CC + c], s);
#pragma unroll
            for (int j = 0; j < 4; ++j) s = fmaf(xv[4 + j], wah[j * CC + c], s);
            e[c] = wave_allreduce_add(s, bidx32);
        }

        // online softmax-weighted accumulation (branch is wave-uniform)
#pragma unroll
        for (int c = 0; c < CC; ++c) {
            if (e[c] > m[c]) {
                const float s = __expf(m[c] - e[c]);   // 0 when m == -inf
                l[c] = l[c] * s + 1.0f;
#pragma unroll
                for (int j = 0; j < 8; ++j) acc[c][j] = fmaf(acc[c][j], s, xv[j]);
                m[c] = e[c];
            } else {
                const float pe = __expf(e[c] - m[c]);
                l[c] += pe;
#pragma unroll
                for (int j = 0; j < 8; ++j) acc[c][j] = fmaf(pe, xv[j], acc[c][j]);
            }
        }
    }

    // ---- combine the 4 waves ----
    __shared__ float s_ml[4][CC][2];
    __shared__ float s_acc[CC][DD];   // 10 KB

    if (lane == 0) {
#pragma unroll
        for (int c = 0; c < CC; ++c) {
            s_ml[wid][c][0] = m[c];
            s_ml[wid][c][1] = l[c];
        }
    }
    __syncthreads();

    float mb[CC], lb[CC], cw[CC];
#pragma unroll
    for (int c = 0; c < CC; ++c) {
        float mm = s_ml[0][c][0];
#pragma unroll
        for (int w = 1; w < 4; ++w) mm = fmaxf(mm, s_ml[w][c][0]);
        mb[c] = mm;
        float ll = 0.0f;
#pragma unroll
        for (int w = 0; w < 4; ++w) ll += __expf(s_ml[w][c][0] - mm) * s_ml[w][c][1];
        lb[c] = ll;
        cw[c] = __expf(s_ml[wid][c][0] - mm);   // this wave's rescale coeff
    }

    // waves deposit (rescaled) accumulators into LDS sequentially
    for (int w = 0; w < 4; ++w) {
        if (wid == w) {
#pragma unroll
            for (int c = 0; c < CC; ++c) {
#pragma unroll
                for (int j = 0; j < 8; ++j) {
                    const int d = (j < 4) ? (d0 + j) : (d1 + j - 4);
                    const float v = acc[c][j] * cw[c];
                    if (w == 0) s_acc[c][d] = v;
                    else        s_acc[c][d] += v;
                }
            }
        }
        __syncthreads();
    }

    // write block partials to workspace
    float* accp = acc_ws + (size_t)blk * CC * DD;
    const float* sa = &s_acc[0][0];
    for (int idx = tid; idx < CC * DD; idx += 256) accp[idx] = sa[idx];
    if (tid < CC) {
        ml_ws[((size_t)blk * CC + tid) * 2 + 0] = mb[tid];
        ml_ws[((size_t)blk * CC + tid) * 2 + 1] = lb[tid];
    }
}

// Pass 2: one block per (b,c). Combine S segment partials, normalize,
// epilogue p = tanh(v.w + b), r = p*v, write all three outputs.
__global__ __launch_bounds__(256)
void capsule_pass2(const float* __restrict__ acc_ws, const float* __restrict__ ml_ws,
                   const float* __restrict__ lin_w, const float* __restrict__ lin_b,
                   float* __restrict__ p_out, float* __restrict__ v_out,
                   float* __restrict__ r_out, int S)
{
    const int bc  = blockIdx.x;          // 0..B*C-1
    const int b   = bc / CC;
    const int c   = bc % CC;
    const int tid = threadIdx.x;

    __shared__ float s_w[64];
    __shared__ float s_red[4];
    __shared__ float s_p;

    // global max over segments (all threads redundantly; identical order -> identical value)
    float mg = -INFINITY;
    for (int s = 0; s < S; ++s)
        mg = fmaxf(mg, ml_ws[(((size_t)b * S + s) * CC + c) * 2]);
    float lg = 0.0f;
    for (int s = 0; s < S; ++s) {
        const float mw = ml_ws[(((size_t)b * S + s) * CC + c) * 2];
        const float lw = ml_ws[(((size_t)b * S + s) * CC + c) * 2 + 1];
        const float w  = __expf(mw - mg);
        lg += w * lw;
        if (tid == 0) s_w[s] = w;
    }
    __syncthreads();

    const float inv_l = 1.0f / lg;
    float v0 = 0.0f, v1 = 0.0f;
    for (int s = 0; s < S; ++s) {
        const float* ap = acc_ws + (((size_t)b * S + s) * CC + c) * DD;
        const float w = s_w[s];
        v0 = fmaf(w, ap[tid], v0);
        v1 = fmaf(w, ap[tid + 256], v1);
    }
    v0 *= inv_l;
    v1 *= inv_l;

    v_out[(size_t)bc * DD + tid]       = v0;
    v_out[(size_t)bc * DD + tid + 256] = v1;

    // dot(v, lin_w)
    float part = v0 * lin_w[tid] + v1 * lin_w[tid + 256];
#pragma unroll
    for (int off = 1; off < 64; off <<= 1) part += __shfl_xor(part, off, 64);
    if ((tid & 63) == 0) s_red[tid >> 6] = part;
    __syncthreads();
    if (tid == 0) {
        const float dot = s_red[0] + s_red[1] + s_red[2] + s_red[3] + lin_b[0];
        const float p = tanhf(dot);
        s_p = p;
        p_out[bc] = p;
    }
    __syncthreads();
    const float p = s_p;
    r_out[(size_t)bc * DD + tid]       = p * v0;
    r_out[(size_t)bc * DD + tid + 256] = p * v1;
}

extern "C" void kernel_launch(void* const* d_in, const int* in_sizes, int n_in,
                              void* d_out, int out_size, void* d_ws, size_t ws_size,
                              hipStream_t stream) {
    const float* x   = (const float*)d_in[0];
    const float* Wa  = (const float*)d_in[1];
    const float* lw  = (const float*)d_in[2];
    const float* lb  = (const float*)d_in[3];

    float* out   = (float*)d_out;
    float* p_out = out;                       // (B, C)
    float* v_out = out + BB * CC;             // (B, C, D)
    float* r_out = v_out + BB * CC * DD;      // (B, C, D)

    // choose segment count to fit workspace: need B*S*C*(D+2) floats
    int S = 32;
    while (S > 1 && (size_t)BB * S * CC * (DD + 2) * sizeof(float) > ws_size) S >>= 1;
    const int rows_per_seg = NN / S;

    float* acc_ws = (float*)d_ws;                        // B*S*C*D
    float* ml_ws  = acc_ws + (size_t)BB * S * CC * DD;   // B*S*C*2

    capsule_pass1<<<dim3(BB * S), dim3(256), 0, stream>>>(x, Wa, acc_ws, ml_ws, S, rows_per_seg);
    capsule_pass2<<<dim3(BB * CC), dim3(256), 0, stream>>>(acc_ws, ml_ws, lw, lb,
                                                           p_out, v_out, r_out, S);
}